// Round 4
// baseline (30.327 us; speedup 1.0000x reference)
//
#include <hip/hip_runtime.h>
#include <math.h>

#define NG 1024          // N_GAUSS (power of two, = sort size)
#define LOG2E 1.4426950408889634f

// sorted record: r0=(px,py,A2,B2) r1=(C2,op,cr,cg) r2=(cb,0,0,0)
// power_log2 = A2*dx^2 + C2*dy^2 + B2*dx*dy   (A2 = -0.5*log2e*A, etc.)

__device__ inline unsigned long long bstage_shfl(unsigned long long key,
                                                 int tid, int j, int k) {
    unsigned long long partner = __shfl_xor(key, j, 64);
    bool lower = (tid & j) == 0;
    bool asc   = (tid & k) == 0;
    return ((key < partner) == (lower == asc)) ? key : partner;
}

// ----------------------------------------------- fused preprocess + sort
// One 1024-thread block. Phase 1: cov2d/depth chain for gaussian tid.
// Phase 2: bitonic sort of (depth|idx) keys (shfl intra-wave, LDS cross-wave).
// Phase 3: thread tid (= sorted rank) finishes prep (conic/SH/bbox) for the
// gaussian it owns and writes records directly to sorted slots.
__global__ void __launch_bounds__(NG) prepsort_kernel(
    const float* __restrict__ means3D, const float* __restrict__ opacities,
    const float* __restrict__ scales,  const float* __restrict__ rotations,
    const float* __restrict__ shs,     const float* __restrict__ view_mat,
    const float* __restrict__ proj_mat,const float* __restrict__ cam_pos,
    const float* __restrict__ tanx_p,  const float* __restrict__ tany_p,
    const int* __restrict__ h_p,       const int* __restrict__ w_p,
    float4* __restrict__ sbbox, float4* __restrict__ srec, int N)
{
    __shared__ unsigned long long sk[NG];
    __shared__ float4 sabc[NG];   // a, b, c, op
    __shared__ float2 spxy[NG];   // px, py
    int tid = threadIdx.x;

    float tanx = tanx_p[0], tany = tany_p[0];
    float Wf = (float)w_p[0], Hf = (float)h_p[0];
    float fx = Wf / (2.f * tanx), fy = Hf / (2.f * tany);
    const float* V = view_mat;   // row-major 4x4

    // ---------------- phase 1: cov2d + depth for gaussian `tid`
    float deptht = 1e10f;
    if (tid < N) {
        float mx = means3D[3*tid], my = means3D[3*tid+1], mz = means3D[3*tid+2];
        float qr = rotations[4*tid],   qx = rotations[4*tid+1];
        float qy = rotations[4*tid+2], qz = rotations[4*tid+3];
        float qn = sqrtf(qr*qr + qx*qx + qy*qy + qz*qz);
        qr /= qn; qx /= qn; qy /= qn; qz /= qn;
        float sx = scales[3*tid], sy = scales[3*tid+1], sz = scales[3*tid+2];
        float R00 = 1.f-2.f*(qy*qy+qz*qz), R01 = 2.f*(qx*qy-qr*qz), R02 = 2.f*(qx*qz+qr*qy);
        float R10 = 2.f*(qx*qy+qr*qz), R11 = 1.f-2.f*(qx*qx+qz*qz), R12 = 2.f*(qy*qz-qr*qx);
        float R20 = 2.f*(qx*qz-qr*qy), R21 = 2.f*(qy*qz+qr*qx), R22 = 1.f-2.f*(qx*qx+qy*qy);
        float M00=R00*sx, M01=R01*sy, M02=R02*sz;
        float M10=R10*sx, M11=R11*sy, M12=R12*sz;
        float M20=R20*sx, M21=R21*sy, M22=R22*sz;
        float S00 = M00*M00+M01*M01+M02*M02;
        float S01 = M00*M10+M01*M11+M02*M12;
        float S02 = M00*M20+M01*M21+M02*M22;
        float S11 = M10*M10+M11*M11+M12*M12;
        float S12 = M10*M20+M11*M21+M12*M22;
        float S22 = M20*M20+M21*M21+M22*M22;

        float t0 = V[0]*mx + V[1]*my + V[2]*mz  + V[3];
        float t1 = V[4]*mx + V[5]*my + V[6]*mz  + V[7];
        float t2 = V[8]*mx + V[9]*my + V[10]*mz + V[11];
        bool valid_z = t2 > 0.2f;
        float tzs = valid_z ? t2 : 1.0f;
        float limx = 1.3f*tanx, limy = 1.3f*tany;
        float txc = fminf(fmaxf(t0/tzs, -limx), limx) * tzs;
        float tyc = fminf(fmaxf(t1/tzs, -limy), limy) * tzs;
        float inv_tz = 1.f / tzs;
        float J00 = fx*inv_tz, J02 = -fx*txc*inv_tz*inv_tz;
        float J11 = fy*inv_tz, J12 = -fy*tyc*inv_tz*inv_tz;
        float T200 = J00*V[0] + J02*V[8];
        float T201 = J00*V[1] + J02*V[9];
        float T202 = J00*V[2] + J02*V[10];
        float T210 = J11*V[4] + J12*V[8];
        float T211 = J11*V[5] + J12*V[9];
        float T212 = J11*V[6] + J12*V[10];
        float u0 = S00*T200 + S01*T201 + S02*T202;
        float u1 = S01*T200 + S11*T201 + S12*T202;
        float u2 = S02*T200 + S12*T201 + S22*T202;
        float cov00 = T200*u0 + T201*u1 + T202*u2;
        float cov01 = T210*u0 + T211*u1 + T212*u2;
        float v0 = S00*T210 + S01*T211 + S02*T212;
        float v1 = S01*T210 + S11*T211 + S12*T212;
        float v2 = S02*T210 + S12*T211 + S22*T212;
        float cov11 = T210*v0 + T211*v1 + T212*v2;
        float a = cov00 + 0.3f;
        float c = cov11 + 0.3f;
        float b = cov01;
        float det = a*c - b*b;
        bool valid = valid_z && (det > 0.f);
        float op = valid ? opacities[tid] : 0.f;

        const float* P = proj_mat;
        float ph0 = P[0]*mx  + P[1]*my  + P[2]*mz  + P[3];
        float ph1 = P[4]*mx  + P[5]*my  + P[6]*mz  + P[7];
        float ph3 = P[12]*mx + P[13]*my + P[14]*mz + P[15];
        float pw = 1.f / (ph3 + 1e-7f);
        float px = ((ph0*pw + 1.f)*Wf - 1.f)*0.5f;
        float py = ((ph1*pw + 1.f)*Hf - 1.f)*0.5f;

        sabc[tid] = make_float4(a, b, c, op);
        spxy[tid] = make_float2(px, py);
        deptht = valid ? t2 : 1e10f;
    }
    __syncthreads();   // sabc/spxy visible before phase 3 reads

    // ---------------- phase 2: bitonic sort of (depth | idx)
    unsigned long long key =
        ((unsigned long long)__float_as_uint(deptht) << 32) | (unsigned)tid;
    for (int k = 2; k <= 64; k <<= 1)
        for (int j = k >> 1; j >= 1; j >>= 1)
            key = bstage_shfl(key, tid, j, k);
    for (int k = 128; k <= NG; k <<= 1) {
        for (int j = k >> 1; j >= 64; j >>= 1) {
            sk[tid] = key;
            __syncthreads();
            unsigned long long partner = sk[tid ^ j];
            bool lower = (tid & j) == 0;
            bool asc   = (tid & k) == 0;
            key = ((key < partner) == (lower == asc)) ? key : partner;
            __syncthreads();
        }
        for (int j = 32; j >= 1; j >>= 1)
            key = bstage_shfl(key, tid, j, k);
    }

    // ---------------- phase 3: finish prep for owned (sorted) gaussian
    int src = (int)(key & (NG - 1));
    if (tid >= N) return;
    float4 abc = sabc[src];
    float2 pxy = spxy[src];
    float a = abc.x, b = abc.y, c = abc.z, op = abc.w;
    float det = a*c - b*b;
    float inv_det = (det > 0.f) ? (1.f/det) : 0.f;
    float Aq = c*inv_det, Bq = -b*inv_det, Cq = a*inv_det;

    // bbox from exact alpha>=1/255 ellipse: x-extent = sqrt(tau*a)
    float tau = 2.f * logf(255.f * fmaxf(op, 1e-20f));
    bool has = (op > 0.f) && (op * 255.f > 1.f) && (tau > 0.f);
    float rx = has ? (sqrtf(tau * a) + 0.01f) : 0.f;
    float ry = has ? (sqrtf(tau * c) + 0.01f) : 0.f;
    sbbox[tid] = has ? make_float4(pxy.x - rx, pxy.y - ry, pxy.x + rx, pxy.y + ry)
                     : make_float4(1e9f, 1e9f, -1e9f, -1e9f);

    // SH eval for src
    float mx = means3D[3*src], my = means3D[3*src+1], mz = means3D[3*src+2];
    float dxm = mx - cam_pos[0], dym = my - cam_pos[1], dzm = mz - cam_pos[2];
    float dn = sqrtf(dxm*dxm + dym*dym + dzm*dzm);
    float X = dxm/dn, Y = dym/dn, Z = dzm/dn;
    float xx = X*X, yy = Y*Y, zz = Z*Z;
    float xy = X*Y, yz = Y*Z, xz = X*Z;
    float col[3];
    #pragma unroll
    for (int ch = 0; ch < 3; ch++) {
        const float* s = shs + src*48 + ch;   // (N,16,3): s[k*3] = coeff k
        float res = 0.28209479177387814f * s[0];
        res += -0.4886025119029199f * Y * s[3]
             +  0.4886025119029199f * Z * s[6]
             -  0.4886025119029199f * X * s[9];
        res +=  1.0925484305920792f * xy * s[12]
             + (-1.0925484305920792f) * yz * s[15]
             +  0.31539156525252005f * (2.f*zz - xx - yy) * s[18]
             + (-1.0925484305920792f) * xz * s[21]
             +  0.5462742152960396f * (xx - yy) * s[24];
        res += -0.5900435899266435f * Y * (3.f*xx - yy) * s[27]
             +  2.890611442640554f  * xy * Z * s[30]
             + (-0.4570457994644658f) * Y * (4.f*zz - xx - yy) * s[33]
             +  0.3731763325901154f  * Z * (2.f*zz - 3.f*xx - 3.f*yy) * s[36]
             + (-0.4570457994644658f) * X * (4.f*zz - xx - yy) * s[39]
             +  1.445305721320277f   * Z * (xx - yy) * s[42]
             + (-0.5900435899266435f) * X * (xx - yy - zz) * s[45];
        col[ch] = fmaxf(res + 0.5f, 0.f);
    }

    srec[tid*3 + 0] = make_float4(pxy.x, pxy.y, -0.5f*LOG2E*Aq, -LOG2E*Bq);
    srec[tid*3 + 1] = make_float4(-0.5f*LOG2E*Cq, op, col[0], col[1]);
    srec[tid*3 + 2] = make_float4(col[2], 0.f, 0.f, 0.f);
}

// --------------------------------------------------------------- rasterize
// One wave per 8x8 tile. Per 64-gaussian chunk: lane g bbox-tests gaussian g,
// ballot -> order-preserving LDS compaction -> counted unrolled blend loop
// with wave-uniform (scalar) record loads.
__global__ void __launch_bounds__(64) render_kernel(
    const float4* __restrict__ sbbox,
    const float4* __restrict__ srec,
    const float* __restrict__ background,
    float* __restrict__ out,
    int N, int W, int HW)
{
    __shared__ int hidx[64];
    int tile = blockIdx.x;
    int tilesX = W >> 3;
    int tx = tile % tilesX, ty = tile / tilesX;
    int lane = threadIdx.x;
    int lx = lane & 7, ly = lane >> 3;
    float pixx = (float)(tx*8 + lx);
    float pixy = (float)(ty*8 + ly);
    float x0 = (float)(tx*8), x1 = x0 + 7.f;
    float y0 = (float)(ty*8), y1 = y0 + 7.f;

    float T = 1.f, Cr = 0.f, Cg = 0.f, Cb = 0.f;

    for (int base = 0; base < N; base += 64) {
        int gi = base + lane;
        float4 bb = (gi < N) ? sbbox[gi] : make_float4(1e9f,1e9f,-1e9f,-1e9f);
        bool hit = (bb.x <= x1) & (bb.z >= x0) & (bb.y <= y1) & (bb.w >= y0);
        unsigned long long mask = __ballot(hit);
        int cnt = __popcll(mask);
        if (cnt) {
            if (hit) {
                int pos = __popcll(mask & ((1ull << lane) - 1ull));
                hidx[pos] = gi;
            }
            __syncthreads();   // single wave: cheap lgkmcnt+barrier
            #pragma unroll 4
            for (int h = 0; h < cnt; h++) {
                int gg = __builtin_amdgcn_readfirstlane(hidx[h]);
                float4 r0 = srec[gg*3 + 0];
                float4 r1 = srec[gg*3 + 1];
                float4 r2 = srec[gg*3 + 2];
                float dx = r0.x - pixx, dy = r0.y - pixy;
                float p2 = fmaf(r0.z, dx*dx, fmaf(r1.x, dy*dy, r0.w*(dx*dy)));
                float e  = __builtin_amdgcn_exp2f(p2);   // power<=0 guaranteed
                float alpha = fminf(r1.y * e, 0.99f);
                float a2 = (alpha >= (1.f/255.f)) ? alpha : 0.f;
                float w = a2 * T;
                Cr = fmaf(r1.z, w, Cr);
                Cg = fmaf(r1.w, w, Cg);
                Cb = fmaf(r2.x, w, Cb);
                T  = T - a2 * T;
            }
            __syncthreads();   // hidx reuse guard
        }
        if (__all(T < 1e-4f)) break;
    }

    int p = (ty*8 + ly) * W + tx*8 + lx;
    out[p]        = Cr + background[0]*T;
    out[HW + p]   = Cg + background[1]*T;
    out[2*HW + p] = Cb + background[2]*T;
}

// ---------------------------------------------------------------- launcher
extern "C" void kernel_launch(void* const* d_in, const int* in_sizes, int n_in,
                              void* d_out, int out_size, void* d_ws, size_t ws_size,
                              hipStream_t stream) {
    const float* background = (const float*)d_in[0];
    const float* means3D    = (const float*)d_in[1];
    const float* opacities  = (const float*)d_in[2];
    const float* scales     = (const float*)d_in[3];
    const float* rotations  = (const float*)d_in[4];
    const float* shs        = (const float*)d_in[5];
    const float* view_mat   = (const float*)d_in[6];
    const float* proj_mat   = (const float*)d_in[7];
    const float* cam_pos    = (const float*)d_in[8];
    const float* tanx       = (const float*)d_in[9];
    const float* tany       = (const float*)d_in[10];
    const int*   hp         = (const int*)d_in[11];
    const int*   wp         = (const int*)d_in[12];

    int N  = in_sizes[2];        // opacities: (N,1)
    int HW = out_size / 3;
    int W  = 256;                // fixed per problem (H*W == HW)
    int H  = HW / W;
    float* out = (float*)d_out;

    float4* sbbox = (float4*)d_ws;                      // NG float4
    float4* srec  = sbbox + NG;                         // NG*3 float4

    prepsort_kernel<<<1, NG, 0, stream>>>(
        means3D, opacities, scales, rotations, shs, view_mat, proj_mat,
        cam_pos, tanx, tany, hp, wp, sbbox, srec, N);

    int tiles = (W >> 3) * (H >> 3);
    render_kernel<<<tiles, 64, 0, stream>>>(
        sbbox, srec, background, out, N, W, HW);
}

// Round 5
// 22.707 us; speedup vs baseline: 1.3356x; 1.3356x over previous
//
#include <hip/hip_runtime.h>
#include <math.h>

#define NG 1024          // N_GAUSS (power of two)
#define LOG2E 1.4426950408889634f

// record: r0=(px,py,A2,B2) r1=(C2,op,cr,cg) r2=(cb,0,0,0)
// power_log2 = A2*dx^2 + C2*dy^2 + B2*dx*dy   (A2 = -0.5*log2e*A, etc.)

// ---------------------------------------------------------------- preprocess
__global__ void prep_kernel(
    const float* __restrict__ means3D, const float* __restrict__ opacities,
    const float* __restrict__ scales,  const float* __restrict__ rotations,
    const float* __restrict__ shs,     const float* __restrict__ view_mat,
    const float* __restrict__ proj_mat,const float* __restrict__ cam_pos,
    const float* __restrict__ tanx_p,  const float* __restrict__ tany_p,
    const int* __restrict__ h_p,       const int* __restrict__ w_p,
    float* __restrict__ depth, float4* __restrict__ bbox,
    float4* __restrict__ rec, int N)
{
    int i = blockIdx.x * blockDim.x + threadIdx.x;
    if (i >= N) return;
    float tanx = tanx_p[0], tany = tany_p[0];
    float Wf = (float)w_p[0], Hf = (float)h_p[0];
    float fx = Wf / (2.f * tanx), fy = Hf / (2.f * tany);

    float mx = means3D[3*i], my = means3D[3*i+1], mz = means3D[3*i+2];

    float qr = rotations[4*i],   qx = rotations[4*i+1];
    float qy = rotations[4*i+2], qz = rotations[4*i+3];
    float qn = sqrtf(qr*qr + qx*qx + qy*qy + qz*qz);
    qr /= qn; qx /= qn; qy /= qn; qz /= qn;
    float sx = scales[3*i], sy = scales[3*i+1], sz = scales[3*i+2];
    float R00 = 1.f-2.f*(qy*qy+qz*qz), R01 = 2.f*(qx*qy-qr*qz), R02 = 2.f*(qx*qz+qr*qy);
    float R10 = 2.f*(qx*qy+qr*qz), R11 = 1.f-2.f*(qx*qx+qz*qz), R12 = 2.f*(qy*qz-qr*qx);
    float R20 = 2.f*(qx*qz-qr*qy), R21 = 2.f*(qy*qz+qr*qx), R22 = 1.f-2.f*(qx*qx+qy*qy);
    float M00=R00*sx, M01=R01*sy, M02=R02*sz;
    float M10=R10*sx, M11=R11*sy, M12=R12*sz;
    float M20=R20*sx, M21=R21*sy, M22=R22*sz;
    float S00 = M00*M00+M01*M01+M02*M02;
    float S01 = M00*M10+M01*M11+M02*M12;
    float S02 = M00*M20+M01*M21+M02*M22;
    float S11 = M10*M10+M11*M11+M12*M12;
    float S12 = M10*M20+M11*M21+M12*M22;
    float S22 = M20*M20+M21*M21+M22*M22;

    const float* V = view_mat;  // row-major 4x4
    float t0 = V[0]*mx + V[1]*my + V[2]*mz  + V[3];
    float t1 = V[4]*mx + V[5]*my + V[6]*mz  + V[7];
    float t2 = V[8]*mx + V[9]*my + V[10]*mz + V[11];
    bool valid_z = t2 > 0.2f;
    float tzs = valid_z ? t2 : 1.0f;
    float limx = 1.3f*tanx, limy = 1.3f*tany;
    float txc = fminf(fmaxf(t0/tzs, -limx), limx) * tzs;
    float tyc = fminf(fmaxf(t1/tzs, -limy), limy) * tzs;
    float inv_tz = 1.f / tzs;
    float J00 = fx*inv_tz, J02 = -fx*txc*inv_tz*inv_tz;
    float J11 = fy*inv_tz, J12 = -fy*tyc*inv_tz*inv_tz;
    float T200 = J00*V[0] + J02*V[8];
    float T201 = J00*V[1] + J02*V[9];
    float T202 = J00*V[2] + J02*V[10];
    float T210 = J11*V[4] + J12*V[8];
    float T211 = J11*V[5] + J12*V[9];
    float T212 = J11*V[6] + J12*V[10];
    float u0 = S00*T200 + S01*T201 + S02*T202;
    float u1 = S01*T200 + S11*T201 + S12*T202;
    float u2 = S02*T200 + S12*T201 + S22*T202;
    float cov00 = T200*u0 + T201*u1 + T202*u2;
    float cov01 = T210*u0 + T211*u1 + T212*u2;
    float v0 = S00*T210 + S01*T211 + S02*T212;
    float v1 = S01*T210 + S11*T211 + S12*T212;
    float v2 = S02*T210 + S12*T211 + S22*T212;
    float cov11 = T210*v0 + T211*v1 + T212*v2;
    float a = cov00 + 0.3f;
    float c = cov11 + 0.3f;
    float b = cov01;
    float det = a*c - b*b;
    bool valid = valid_z && (det > 0.f);
    float inv_det = (det > 0.f) ? (1.f/det) : 0.f;
    float Aq = c*inv_det, Bq = -b*inv_det, Cq = a*inv_det;

    const float* P = proj_mat;
    float ph0 = P[0]*mx  + P[1]*my  + P[2]*mz  + P[3];
    float ph1 = P[4]*mx  + P[5]*my  + P[6]*mz  + P[7];
    float ph3 = P[12]*mx + P[13]*my + P[14]*mz + P[15];
    float pw = 1.f / (ph3 + 1e-7f);
    float px = ((ph0*pw + 1.f)*Wf - 1.f)*0.5f;
    float py = ((ph1*pw + 1.f)*Hf - 1.f)*0.5f;

    float dxm = mx - cam_pos[0], dym = my - cam_pos[1], dzm = mz - cam_pos[2];
    float dn = sqrtf(dxm*dxm + dym*dym + dzm*dzm);
    float X = dxm/dn, Y = dym/dn, Z = dzm/dn;
    float xx = X*X, yy = Y*Y, zz = Z*Z;
    float xy = X*Y, yz = Y*Z, xz = X*Z;
    float col[3];
    #pragma unroll
    for (int ch = 0; ch < 3; ch++) {
        const float* s = shs + i*48 + ch;   // (N,16,3): s[k*3] = coeff k
        float res = 0.28209479177387814f * s[0];
        res += -0.4886025119029199f * Y * s[3]
             +  0.4886025119029199f * Z * s[6]
             -  0.4886025119029199f * X * s[9];
        res +=  1.0925484305920792f * xy * s[12]
             + (-1.0925484305920792f) * yz * s[15]
             +  0.31539156525252005f * (2.f*zz - xx - yy) * s[18]
             + (-1.0925484305920792f) * xz * s[21]
             +  0.5462742152960396f * (xx - yy) * s[24];
        res += -0.5900435899266435f * Y * (3.f*xx - yy) * s[27]
             +  2.890611442640554f  * xy * Z * s[30]
             + (-0.4570457994644658f) * Y * (4.f*zz - xx - yy) * s[33]
             +  0.3731763325901154f  * Z * (2.f*zz - 3.f*xx - 3.f*yy) * s[36]
             + (-0.4570457994644658f) * X * (4.f*zz - xx - yy) * s[39]
             +  1.445305721320277f   * Z * (xx - yy) * s[42]
             + (-0.5900435899266435f) * X * (xx - yy - zz) * s[45];
        col[ch] = fmaxf(res + 0.5f, 0.f);
    }

    float op = valid ? opacities[i] : 0.f;
    depth[i] = valid ? t2 : 1e10f;

    // exact alpha>=1/255 ellipse extents: rx = sqrt(tau*a), tau = 2 ln(255 op)
    float tau = 2.f * logf(255.f * fmaxf(op, 1e-20f));
    bool has = valid && (op * 255.f > 1.f) && (tau > 0.f);
    float rx = has ? (sqrtf(tau * a) + 0.01f) : 0.f;
    float ry = has ? (sqrtf(tau * c) + 0.01f) : 0.f;
    bbox[i] = has ? make_float4(px - rx, py - ry, px + rx, py + ry)
                  : make_float4(1e9f, 1e9f, -1e9f, -1e9f);

    rec[i*3 + 0] = make_float4(px, py, -0.5f*LOG2E*Aq, -LOG2E*Bq);
    rec[i*3 + 1] = make_float4(-0.5f*LOG2E*Cq, op, col[0], col[1]);
    rec[i*3 + 2] = make_float4(col[2], 0.f, 0.f, 0.f);
}

// --------------------------------------------------------------- rasterize
// One wave per 8x8 tile. Gather hits via bbox ballot-compaction (index
// order), sort (depth|idx) keys locally (shfl bitonic if cnt<=64, LDS
// bitonic otherwise), then blend front-to-back with scalar record loads.
__device__ inline unsigned long long bstage_shfl(unsigned long long key,
                                                 int tid, int j, int k) {
    unsigned long long partner = __shfl_xor(key, j, 64);
    bool lower = (tid & j) == 0;
    bool asc   = (tid & k) == 0;
    return ((key < partner) == (lower == asc)) ? key : partner;
}

__global__ void __launch_bounds__(64) render_kernel(
    const float* __restrict__ depth,
    const float4* __restrict__ bbox,
    const float4* __restrict__ rec,
    const float* __restrict__ background,
    float* __restrict__ out,
    int N, int W, int HW)
{
    __shared__ unsigned long long skey[NG];
    int tile = blockIdx.x;
    int tilesX = W >> 3;
    int tx = tile % tilesX, ty = tile / tilesX;
    int lane = threadIdx.x;
    int lx = lane & 7, ly = lane >> 3;
    float pixx = (float)(tx*8 + lx);
    float pixy = (float)(ty*8 + ly);
    float x0 = (float)(tx*8), x1 = x0 + 7.f;
    float y0 = (float)(ty*8), y1 = y0 + 7.f;

    // ---- gather hit list (index-ordered)
    int cnt = 0;
    for (int base = 0; base < N; base += 64) {
        int gi = base + lane;
        bool hit = false;
        float dz = 0.f;
        if (gi < N) {
            float4 bb = bbox[gi];
            dz = depth[gi];
            hit = (bb.x <= x1) & (bb.z >= x0) & (bb.y <= y1) & (bb.w >= y0);
        }
        unsigned long long mask = __ballot(hit);
        if (hit) {
            int pos = cnt + __popcll(mask & ((1ull << lane) - 1ull));
            skey[pos] = ((unsigned long long)__float_as_uint(dz) << 32) | (unsigned)gi;
        }
        cnt += __popcll(mask);
    }
    __syncthreads();

    float T = 1.f, Cr = 0.f, Cg = 0.f, Cb = 0.f;
    if (cnt > 0) {
        // ---- local depth sort
        if (cnt <= 64) {
            unsigned long long key = (lane < cnt) ? skey[lane] : ~0ull;
            for (int k = 2; k <= 64; k <<= 1)
                for (int j = k >> 1; j >= 1; j >>= 1)
                    key = bstage_shfl(key, lane, j, k);
            skey[lane] = key;
            __syncthreads();
        } else {
            int P = 128;
            while (P < cnt) P <<= 1;
            for (int i2 = cnt + lane; i2 < P; i2 += 64) skey[i2] = ~0ull;
            __syncthreads();
            for (int k = 2; k <= P; k <<= 1) {
                for (int j = k >> 1; j >= 1; j >>= 1) {
                    for (int i2 = lane; i2 < P; i2 += 64) {
                        int ixj = i2 ^ j;
                        if (ixj > i2) {
                            bool asc = (i2 & k) == 0;
                            unsigned long long u = skey[i2], v = skey[ixj];
                            if ((u > v) == asc) { skey[i2] = v; skey[ixj] = u; }
                        }
                    }
                    __syncthreads();
                }
            }
        }

        // ---- blend front-to-back
        for (int h = 0; h < cnt; h++) {
            int gg = __builtin_amdgcn_readfirstlane((int)(unsigned)skey[h]);
            float4 r0 = rec[gg*3 + 0];
            float4 r1 = rec[gg*3 + 1];
            float4 r2 = rec[gg*3 + 2];
            float dx = r0.x - pixx, dy = r0.y - pixy;
            float p2 = fmaf(r0.z, dx*dx, fmaf(r1.x, dy*dy, r0.w*(dx*dy)));
            float e  = __builtin_amdgcn_exp2f(p2);     // power<=0 guaranteed
            float alpha = fminf(r1.y * e, 0.99f);
            float a2 = (alpha >= (1.f/255.f)) ? alpha : 0.f;
            float w = a2 * T;
            Cr = fmaf(r1.z, w, Cr);
            Cg = fmaf(r1.w, w, Cg);
            Cb = fmaf(r2.x, w, Cb);
            T  = T - a2 * T;
            if (__all(T < 1e-4f)) break;
        }
    }

    int p = (ty*8 + ly) * W + tx*8 + lx;
    out[p]        = Cr + background[0]*T;
    out[HW + p]   = Cg + background[1]*T;
    out[2*HW + p] = Cb + background[2]*T;
}

// ---------------------------------------------------------------- launcher
extern "C" void kernel_launch(void* const* d_in, const int* in_sizes, int n_in,
                              void* d_out, int out_size, void* d_ws, size_t ws_size,
                              hipStream_t stream) {
    const float* background = (const float*)d_in[0];
    const float* means3D    = (const float*)d_in[1];
    const float* opacities  = (const float*)d_in[2];
    const float* scales     = (const float*)d_in[3];
    const float* rotations  = (const float*)d_in[4];
    const float* shs        = (const float*)d_in[5];
    const float* view_mat   = (const float*)d_in[6];
    const float* proj_mat   = (const float*)d_in[7];
    const float* cam_pos    = (const float*)d_in[8];
    const float* tanx       = (const float*)d_in[9];
    const float* tany       = (const float*)d_in[10];
    const int*   hp         = (const int*)d_in[11];
    const int*   wp         = (const int*)d_in[12];

    int N  = in_sizes[2];        // opacities: (N,1)
    int HW = out_size / 3;
    int W  = 256;                // fixed per problem (H*W == HW)
    int H  = HW / W;
    float* out = (float*)d_out;

    float*  depth = (float*)d_ws;                       // NG floats
    float4* bbox  = (float4*)(depth + NG);              // NG float4
    float4* rec   = bbox + NG;                          // NG*3 float4

    prep_kernel<<<16, 64, 0, stream>>>(
        means3D, opacities, scales, rotations, shs, view_mat, proj_mat,
        cam_pos, tanx, tany, hp, wp, depth, bbox, rec, N);

    int tiles = (W >> 3) * (H >> 3);
    render_kernel<<<tiles, 64, 0, stream>>>(
        depth, bbox, rec, background, out, N, W, HW);
}

// Round 6
// 20.559 us; speedup vs baseline: 1.4751x; 1.1045x over previous
//
#include <hip/hip_runtime.h>
#include <math.h>

#define NG 1024          // N_GAUSS (power of two)
#define LOG2E 1.4426950408889634f

// record: r0=(px,py,A2,B2) r1=(C2,op,cr,cg) r2=(cb,0,0,0)
// power_log2 = A2*dx^2 + C2*dy^2 + B2*dx*dy   (A2 = -0.5*log2e*A, etc.)

// ---------------------------------------------------------------- preprocess
__global__ void prep_kernel(
    const float* __restrict__ means3D, const float* __restrict__ opacities,
    const float* __restrict__ scales,  const float* __restrict__ rotations,
    const float* __restrict__ shs,     const float* __restrict__ view_mat,
    const float* __restrict__ proj_mat,const float* __restrict__ cam_pos,
    const float* __restrict__ tanx_p,  const float* __restrict__ tany_p,
    const int* __restrict__ h_p,       const int* __restrict__ w_p,
    unsigned long long* __restrict__ keys, float4* __restrict__ bbox,
    float4* __restrict__ rec, int N)
{
    int i = blockIdx.x * blockDim.x + threadIdx.x;
    if (i >= N) return;
    float tanx = tanx_p[0], tany = tany_p[0];
    float Wf = (float)w_p[0], Hf = (float)h_p[0];
    float fx = Wf / (2.f * tanx), fy = Hf / (2.f * tany);

    float mx = means3D[3*i], my = means3D[3*i+1], mz = means3D[3*i+2];

    float qr = rotations[4*i],   qx = rotations[4*i+1];
    float qy = rotations[4*i+2], qz = rotations[4*i+3];
    float qn = sqrtf(qr*qr + qx*qx + qy*qy + qz*qz);
    qr /= qn; qx /= qn; qy /= qn; qz /= qn;
    float sx = scales[3*i], sy = scales[3*i+1], sz = scales[3*i+2];
    float R00 = 1.f-2.f*(qy*qy+qz*qz), R01 = 2.f*(qx*qy-qr*qz), R02 = 2.f*(qx*qz+qr*qy);
    float R10 = 2.f*(qx*qy+qr*qz), R11 = 1.f-2.f*(qx*qx+qz*qz), R12 = 2.f*(qy*qz-qr*qx);
    float R20 = 2.f*(qx*qz-qr*qy), R21 = 2.f*(qy*qz+qr*qx), R22 = 1.f-2.f*(qx*qx+qy*qy);
    float M00=R00*sx, M01=R01*sy, M02=R02*sz;
    float M10=R10*sx, M11=R11*sy, M12=R12*sz;
    float M20=R20*sx, M21=R21*sy, M22=R22*sz;
    float S00 = M00*M00+M01*M01+M02*M02;
    float S01 = M00*M10+M01*M11+M02*M12;
    float S02 = M00*M20+M01*M21+M02*M22;
    float S11 = M10*M10+M11*M11+M12*M12;
    float S12 = M10*M20+M11*M21+M12*M22;
    float S22 = M20*M20+M21*M21+M22*M22;

    const float* V = view_mat;  // row-major 4x4
    float t0 = V[0]*mx + V[1]*my + V[2]*mz  + V[3];
    float t1 = V[4]*mx + V[5]*my + V[6]*mz  + V[7];
    float t2 = V[8]*mx + V[9]*my + V[10]*mz + V[11];
    bool valid_z = t2 > 0.2f;
    float tzs = valid_z ? t2 : 1.0f;
    float limx = 1.3f*tanx, limy = 1.3f*tany;
    float txc = fminf(fmaxf(t0/tzs, -limx), limx) * tzs;
    float tyc = fminf(fmaxf(t1/tzs, -limy), limy) * tzs;
    float inv_tz = 1.f / tzs;
    float J00 = fx*inv_tz, J02 = -fx*txc*inv_tz*inv_tz;
    float J11 = fy*inv_tz, J12 = -fy*tyc*inv_tz*inv_tz;
    float T200 = J00*V[0] + J02*V[8];
    float T201 = J00*V[1] + J02*V[9];
    float T202 = J00*V[2] + J02*V[10];
    float T210 = J11*V[4] + J12*V[8];
    float T211 = J11*V[5] + J12*V[9];
    float T212 = J11*V[6] + J12*V[10];
    float u0 = S00*T200 + S01*T201 + S02*T202;
    float u1 = S01*T200 + S11*T201 + S12*T202;
    float u2 = S02*T200 + S12*T201 + S22*T202;
    float cov00 = T200*u0 + T201*u1 + T202*u2;
    float cov01 = T210*u0 + T211*u1 + T212*u2;
    float v0 = S00*T210 + S01*T211 + S02*T212;
    float v1 = S01*T210 + S11*T211 + S12*T212;
    float v2 = S02*T210 + S12*T211 + S22*T212;
    float cov11 = T210*v0 + T211*v1 + T212*v2;
    float a = cov00 + 0.3f;
    float c = cov11 + 0.3f;
    float b = cov01;
    float det = a*c - b*b;
    bool valid = valid_z && (det > 0.f);
    float inv_det = (det > 0.f) ? (1.f/det) : 0.f;
    float Aq = c*inv_det, Bq = -b*inv_det, Cq = a*inv_det;

    const float* P = proj_mat;
    float ph0 = P[0]*mx  + P[1]*my  + P[2]*mz  + P[3];
    float ph1 = P[4]*mx  + P[5]*my  + P[6]*mz  + P[7];
    float ph3 = P[12]*mx + P[13]*my + P[14]*mz + P[15];
    float pw = 1.f / (ph3 + 1e-7f);
    float px = ((ph0*pw + 1.f)*Wf - 1.f)*0.5f;
    float py = ((ph1*pw + 1.f)*Hf - 1.f)*0.5f;

    float dxm = mx - cam_pos[0], dym = my - cam_pos[1], dzm = mz - cam_pos[2];
    float dn = sqrtf(dxm*dxm + dym*dym + dzm*dzm);
    float X = dxm/dn, Y = dym/dn, Z = dzm/dn;
    float xx = X*X, yy = Y*Y, zz = Z*Z;
    float xy = X*Y, yz = Y*Z, xz = X*Z;
    float col[3];
    #pragma unroll
    for (int ch = 0; ch < 3; ch++) {
        const float* s = shs + i*48 + ch;   // (N,16,3): s[k*3] = coeff k
        float res = 0.28209479177387814f * s[0];
        res += -0.4886025119029199f * Y * s[3]
             +  0.4886025119029199f * Z * s[6]
             -  0.4886025119029199f * X * s[9];
        res +=  1.0925484305920792f * xy * s[12]
             + (-1.0925484305920792f) * yz * s[15]
             +  0.31539156525252005f * (2.f*zz - xx - yy) * s[18]
             + (-1.0925484305920792f) * xz * s[21]
             +  0.5462742152960396f * (xx - yy) * s[24];
        res += -0.5900435899266435f * Y * (3.f*xx - yy) * s[27]
             +  2.890611442640554f  * xy * Z * s[30]
             + (-0.4570457994644658f) * Y * (4.f*zz - xx - yy) * s[33]
             +  0.3731763325901154f  * Z * (2.f*zz - 3.f*xx - 3.f*yy) * s[36]
             + (-0.4570457994644658f) * X * (4.f*zz - xx - yy) * s[39]
             +  1.445305721320277f   * Z * (xx - yy) * s[42]
             + (-0.5900435899266435f) * X * (xx - yy - zz) * s[45];
        col[ch] = fmaxf(res + 0.5f, 0.f);
    }

    float op = valid ? opacities[i] : 0.f;
    float dpt = valid ? t2 : 1e10f;
    keys[i] = ((unsigned long long)__float_as_uint(dpt) << 32) | (unsigned)i;

    // exact alpha>=1/255 ellipse extents: rx = sqrt(tau*a), tau = 2 ln(255 op)
    float tau = 2.f * logf(255.f * fmaxf(op, 1e-20f));
    bool has = valid && (op * 255.f > 1.f) && (tau > 0.f);
    float rx = has ? (sqrtf(tau * a) + 0.01f) : 0.f;
    float ry = has ? (sqrtf(tau * c) + 0.01f) : 0.f;
    bbox[i] = has ? make_float4(px - rx, py - ry, px + rx, py + ry)
                  : make_float4(1e9f, 1e9f, -1e9f, -1e9f);

    rec[i*3 + 0] = make_float4(px, py, -0.5f*LOG2E*Aq, -LOG2E*Bq);
    rec[i*3 + 1] = make_float4(-0.5f*LOG2E*Cq, op, col[0], col[1]);
    rec[i*3 + 2] = make_float4(col[2], 0.f, 0.f, 0.f);
}

// --------------------------------------------------------------- rasterize
__device__ inline unsigned long long bstage_shfl(unsigned long long key,
                                                 int tid, int j, int k) {
    unsigned long long partner = __shfl_xor(key, j, 64);
    bool lower = (tid & j) == 0;
    bool asc   = (tid & k) == 0;
    return ((key < partner) == (lower == asc)) ? key : partner;
}

__device__ inline float rlane(float v, int l) {
    return __int_as_float(__builtin_amdgcn_readlane(__float_as_int(v), l));
}

// One wave per 8x8 tile. Gather hits (bbox ballot-compaction, index order),
// local depth sort, then chunked blend: each lane pre-loads ONE hit's record
// (parallel, coalesced), inner loop broadcasts fields via v_readlane —
// no memory access in the blend chain.
__global__ void __launch_bounds__(64) render_kernel(
    const unsigned long long* __restrict__ keys,
    const float4* __restrict__ bbox,
    const float4* __restrict__ rec,
    const float* __restrict__ background,
    float* __restrict__ out,
    int N, int W, int HW)
{
    __shared__ unsigned long long skey[NG];
    int tile = blockIdx.x;
    int tilesX = W >> 3;
    int tx = tile % tilesX, ty = tile / tilesX;
    int lane = threadIdx.x;
    int lx = lane & 7, ly = lane >> 3;
    float pixx = (float)(tx*8 + lx);
    float pixy = (float)(ty*8 + ly);
    float x0 = (float)(tx*8), x1 = x0 + 7.f;
    float y0 = (float)(ty*8), y1 = y0 + 7.f;

    // ---- gather hit list (index-ordered)
    int cnt = 0;
    for (int base = 0; base < N; base += 64) {
        int gi = base + lane;
        bool hit = false;
        unsigned long long k = 0;
        if (gi < N) {
            float4 bb = bbox[gi];
            k = keys[gi];
            hit = (bb.x <= x1) & (bb.z >= x0) & (bb.y <= y1) & (bb.w >= y0);
        }
        unsigned long long mask = __ballot(hit);
        if (hit) {
            int pos = cnt + __popcll(mask & ((1ull << lane) - 1ull));
            skey[pos] = k;
        }
        cnt += __popcll(mask);
    }
    __syncthreads();

    float T = 1.f, Cr = 0.f, Cg = 0.f, Cb = 0.f;
    if (cnt > 0) {
        // ---- local depth sort (keys end up in skey[0..cnt))
        if (cnt <= 64) {
            unsigned long long key = (lane < cnt) ? skey[lane] : ~0ull;
            for (int k = 2; k <= 64; k <<= 1)
                for (int j = k >> 1; j >= 1; j >>= 1)
                    key = bstage_shfl(key, lane, j, k);
            skey[lane] = key;
            __syncthreads();
        } else {
            int P = 128;
            while (P < cnt) P <<= 1;
            for (int i2 = cnt + lane; i2 < P; i2 += 64) skey[i2] = ~0ull;
            __syncthreads();
            for (int k = 2; k <= P; k <<= 1) {
                for (int j = k >> 1; j >= 1; j >>= 1) {
                    for (int i2 = lane; i2 < P; i2 += 64) {
                        int ixj = i2 ^ j;
                        if (ixj > i2) {
                            bool asc = (i2 & k) == 0;
                            unsigned long long u = skey[i2], v = skey[ixj];
                            if ((u > v) == asc) { skey[i2] = v; skey[ixj] = u; }
                        }
                    }
                    __syncthreads();
                }
            }
        }

        // ---- chunked blend: lane owns hit (c+lane); readlane broadcast
        bool dead = false;
        for (int c = 0; c < cnt && !dead; c += 64) {
            int len = min(64, cnt - c);
            int idx = c + lane;
            int gg = (idx < cnt) ? (int)(unsigned)skey[idx] : 0;
            float4 r0 = rec[gg*3 + 0];
            float4 r1 = rec[gg*3 + 1];
            float4 r2 = rec[gg*3 + 2];
            for (int m = 0; m < len; m++) {
                float gpx = rlane(r0.x, m), gpy = rlane(r0.y, m);
                float gA  = rlane(r0.z, m), gB  = rlane(r0.w, m);
                float gC  = rlane(r1.x, m), gop = rlane(r1.y, m);
                float gcr = rlane(r1.z, m), gcg = rlane(r1.w, m);
                float gcb = rlane(r2.x, m);
                float dx = gpx - pixx, dy = gpy - pixy;
                float p2 = fmaf(gA, dx*dx, fmaf(gC, dy*dy, gB*(dx*dy)));
                float e  = __builtin_amdgcn_exp2f(p2);   // power<=0 guaranteed
                float alpha = fminf(gop * e, 0.99f);
                float a2 = (alpha >= (1.f/255.f)) ? alpha : 0.f;
                float w = a2 * T;
                Cr = fmaf(gcr, w, Cr);
                Cg = fmaf(gcg, w, Cg);
                Cb = fmaf(gcb, w, Cb);
                T  = T - a2 * T;
                if ((m & 15) == 15 && __all(T < 1e-4f)) { dead = true; break; }
            }
            if (__all(T < 1e-4f)) dead = true;
        }
    }

    int p = (ty*8 + ly) * W + tx*8 + lx;
    out[p]        = Cr + background[0]*T;
    out[HW + p]   = Cg + background[1]*T;
    out[2*HW + p] = Cb + background[2]*T;
}

// ---------------------------------------------------------------- launcher
extern "C" void kernel_launch(void* const* d_in, const int* in_sizes, int n_in,
                              void* d_out, int out_size, void* d_ws, size_t ws_size,
                              hipStream_t stream) {
    const float* background = (const float*)d_in[0];
    const float* means3D    = (const float*)d_in[1];
    const float* opacities  = (const float*)d_in[2];
    const float* scales     = (const float*)d_in[3];
    const float* rotations  = (const float*)d_in[4];
    const float* shs        = (const float*)d_in[5];
    const float* view_mat   = (const float*)d_in[6];
    const float* proj_mat   = (const float*)d_in[7];
    const float* cam_pos    = (const float*)d_in[8];
    const float* tanx       = (const float*)d_in[9];
    const float* tany       = (const float*)d_in[10];
    const int*   hp         = (const int*)d_in[11];
    const int*   wp         = (const int*)d_in[12];

    int N  = in_sizes[2];        // opacities: (N,1)
    int HW = out_size / 3;
    int W  = 256;                // fixed per problem (H*W == HW)
    int H  = HW / W;
    float* out = (float*)d_out;

    unsigned long long* keys = (unsigned long long*)d_ws;   // NG u64
    float4* bbox = (float4*)(keys + NG);                    // NG float4
    float4* rec  = bbox + NG;                               // NG*3 float4

    prep_kernel<<<16, 64, 0, stream>>>(
        means3D, opacities, scales, rotations, shs, view_mat, proj_mat,
        cam_pos, tanx, tany, hp, wp, keys, bbox, rec, N);

    int tiles = (W >> 3) * (H >> 3);
    render_kernel<<<tiles, 64, 0, stream>>>(
        keys, bbox, rec, background, out, N, W, HW);
}